// Round 3
// baseline (450.620 us; speedup 1.0000x reference)
//
#include <hip/hip_runtime.h>

constexpr int T = 168;
constexpr int P = 16;
constexpr int H = 24;

__device__ __forceinline__ float rcp_f(float x) { return __builtin_amdgcn_rcpf(x); }
__device__ __forceinline__ float sigm_f(float x) { return rcp_f(1.f + __expf(-x)); }
// tanh(x) = 2*sigmoid(2x) - 1
__device__ __forceinline__ float tanh_fast(float x) {
    return fmaf(2.f, rcp_f(1.f + __expf(-2.f * x)), -1.f);
}

// Opaque register pin: erases the value's load provenance so the register
// allocator CANNOT rematerialize the (loop-invariant) load inside the T-loop.
// R1 (VGPR=76) and R2 (VGPR=104) both show LLVM sinking weight loads into the
// loop; this forces the 176 weight floats to stay live in VGPRs.
#define KEEP(v) asm volatile("" : "+v"(v))

// LDS write->read ordering within a single wave: DS ops from one wave execute
// in order; we need the counter drained + a compiler reorder fence.
#define LDS_SYNC() asm volatile("s_waitcnt lgkmcnt(0)" ::: "memory")

// One row per 64-lane wave. Lane u in [0,24): gates {i, g} of unit u.
// Lane 24+u: gates {f, o}. Lanes 48..63 idle (duplicate lane 47, never store).
// No __syncthreads anywhere: all comms are intra-wave (shfl + wave-sync LDS).
__global__ __attribute__((amdgpu_flat_work_group_size(64, 64),
                          amdgpu_waves_per_eu(2, 2)))
void lstm2_wave(const float* __restrict__ x,
                const float* __restrict__ Wih1, const float* __restrict__ Whh1,
                const float* __restrict__ bih1, const float* __restrict__ bhh1,
                const float* __restrict__ Wih2, const float* __restrict__ Whh2,
                const float* __restrict__ bih2, const float* __restrict__ bhh2,
                const float* __restrict__ W1, const float* __restrict__ b1,
                const float* __restrict__ W2, const float* __restrict__ b2,
                float* __restrict__ out)
{
    const int lane = threadIdx.x;                 // 0..63
    const int s    = (lane < 48) ? lane : 47;     // clamp idle lanes onto valid rows
    const int u    = s % H;                       // unit 0..23
    const int half = s / H;                       // 0: {i,g}, 1: {f,o}
    const int q0   = half * H + u;                // i or f gate row
    const int q1   = (2 + half) * H + u;          // g or o gate row
    const int row  = blockIdx.x;

    // ---- weights into registers: 2*(16+24) + 2*(24+24) = 176 floats ----
    float wx0[P], wx1[P];         // Wih1 rows q0, q1
    float wh0[H], wh1[H];         // Whh1 rows q0, q1
    float vx0[H], vx1[H];         // Wih2 rows q0, q1
    float vh0[H], vh1[H];         // Whh2 rows q0, q1
    #pragma unroll
    for (int k = 0; k < P / 4; ++k) {
        float4 a = ((const float4*)(Wih1 + q0 * P))[k];
        float4 b = ((const float4*)(Wih1 + q1 * P))[k];
        wx0[4*k] = a.x; wx0[4*k+1] = a.y; wx0[4*k+2] = a.z; wx0[4*k+3] = a.w;
        wx1[4*k] = b.x; wx1[4*k+1] = b.y; wx1[4*k+2] = b.z; wx1[4*k+3] = b.w;
    }
    #pragma unroll
    for (int k = 0; k < H / 4; ++k) {
        float4 a = ((const float4*)(Whh1 + q0 * H))[k];
        float4 b = ((const float4*)(Whh1 + q1 * H))[k];
        wh0[4*k] = a.x; wh0[4*k+1] = a.y; wh0[4*k+2] = a.z; wh0[4*k+3] = a.w;
        wh1[4*k] = b.x; wh1[4*k+1] = b.y; wh1[4*k+2] = b.z; wh1[4*k+3] = b.w;
    }
    #pragma unroll
    for (int k = 0; k < H / 4; ++k) {
        float4 a = ((const float4*)(Wih2 + q0 * H))[k];
        float4 b = ((const float4*)(Wih2 + q1 * H))[k];
        vx0[4*k] = a.x; vx0[4*k+1] = a.y; vx0[4*k+2] = a.z; vx0[4*k+3] = a.w;
        vx1[4*k] = b.x; vx1[4*k+1] = b.y; vx1[4*k+2] = b.z; vx1[4*k+3] = b.w;
    }
    #pragma unroll
    for (int k = 0; k < H / 4; ++k) {
        float4 a = ((const float4*)(Whh2 + q0 * H))[k];
        float4 b = ((const float4*)(Whh2 + q1 * H))[k];
        vh0[4*k] = a.x; vh0[4*k+1] = a.y; vh0[4*k+2] = a.z; vh0[4*k+3] = a.w;
        vh1[4*k] = b.x; vh1[4*k+1] = b.y; vh1[4*k+2] = b.z; vh1[4*k+3] = b.w;
    }
    float b10 = bih1[q0] + bhh1[q0];
    float b11 = bih1[q1] + bhh1[q1];
    float b20 = bih2[q0] + bhh2[q0];
    float b21 = bih2[q1] + bhh2[q1];

    // ---- pin everything loop-invariant into VGPRs (no remat possible) ----
    #pragma unroll
    for (int k = 0; k < P; ++k) { KEEP(wx0[k]); KEEP(wx1[k]); }
    #pragma unroll
    for (int k = 0; k < H; ++k) {
        KEEP(wh0[k]); KEEP(wh1[k]);
        KEEP(vx0[k]); KEEP(vx1[k]);
        KEEP(vh0[k]); KEEP(vh1[k]);
    }
    KEEP(b10); KEEP(b11); KEEP(b20); KEEP(b21);

    __shared__ __align__(16) float h1s[32];   // layer-1 h
    __shared__ __align__(16) float t1s[32];   // tanh(layer-1 h) = layer-2 input
    __shared__ __align__(16) float h2s[32];   // layer-2 h

    if (lane < H) { h1s[lane] = 0.f; t1s[lane] = 0.f; h2s[lane] = 0.f; }
    LDS_SYNC();

    const float* __restrict__ xrow = x + (size_t)row * T * P;  // wave-uniform

    float c1 = 0.f, c2 = 0.f;

    for (int t = 0; t < T; ++t) {
        // ---- layer-1 gates ----
        float g0 = b10, g1 = b11;
        #pragma unroll
        for (int k = 0; k < P; ++k) {
            float xv = xrow[t * P + k];              // uniform -> scalar load
            g0 = fmaf(xv, wx0[k], g0);
            g1 = fmaf(xv, wx1[k], g1);
        }
        #pragma unroll
        for (int k = 0; k < H / 4; ++k) {
            float4 hv = ((const float4*)h1s)[k];
            g0 = fmaf(hv.x, wh0[4*k],   g0);  g1 = fmaf(hv.x, wh1[4*k],   g1);
            g0 = fmaf(hv.y, wh0[4*k+1], g0);  g1 = fmaf(hv.y, wh1[4*k+1], g1);
            g0 = fmaf(hv.z, wh0[4*k+2], g0);  g1 = fmaf(hv.z, wh1[4*k+2], g1);
            g0 = fmaf(hv.w, wh0[4*k+3], g0);  g1 = fmaf(hv.w, wh1[4*k+3], g1);
        }
        // activations: a0 = sigmoid(g0) [i or f]; a1 = tanh(g1) [g] on half 0,
        // sigmoid(g1) [o] on half 1 — branch-free via 2*sigm(2x)-1
        float a0 = sigm_f(g0);
        float px = (half == 0) ? g1 + g1 : g1;
        float sv = sigm_f(px);
        float a1 = (half == 0) ? sv + sv - 1.f : sv;
        // exchange: lane u pulls (f,o) from lane 24+u
        float fa = __shfl(a0, lane + 24);
        float oa = __shfl(a1, lane + 24);
        // state update (valid on lanes < 24; upper lanes compute garbage, unused)
        c1 = fmaf(fa, c1, a0 * a1);                  // f*c + i*tanh(g)
        float h1 = oa * tanh_fast(c1);
        float th1 = tanh_fast(h1);
        if (lane < H) { h1s[lane] = h1; t1s[lane] = th1; }
        LDS_SYNC();

        // ---- layer-2 gates ----
        float g2 = b20, g3 = b21;
        #pragma unroll
        for (int k = 0; k < H / 4; ++k) {
            float4 tv = ((const float4*)t1s)[k];
            g2 = fmaf(tv.x, vx0[4*k],   g2);  g3 = fmaf(tv.x, vx1[4*k],   g3);
            g2 = fmaf(tv.y, vx0[4*k+1], g2);  g3 = fmaf(tv.y, vx1[4*k+1], g3);
            g2 = fmaf(tv.z, vx0[4*k+2], g2);  g3 = fmaf(tv.z, vx1[4*k+2], g3);
            g2 = fmaf(tv.w, vx0[4*k+3], g2);  g3 = fmaf(tv.w, vx1[4*k+3], g3);
        }
        #pragma unroll
        for (int k = 0; k < H / 4; ++k) {
            float4 hv = ((const float4*)h2s)[k];
            g2 = fmaf(hv.x, vh0[4*k],   g2);  g3 = fmaf(hv.x, vh1[4*k],   g3);
            g2 = fmaf(hv.y, vh0[4*k+1], g2);  g3 = fmaf(hv.y, vh1[4*k+1], g3);
            g2 = fmaf(hv.z, vh0[4*k+2], g2);  g3 = fmaf(hv.z, vh1[4*k+2], g3);
            g2 = fmaf(hv.w, vh0[4*k+3], g2);  g3 = fmaf(hv.w, vh1[4*k+3], g3);
        }
        float a2 = sigm_f(g2);
        float py = (half == 0) ? g3 + g3 : g3;
        float sw = sigm_f(py);
        float a3 = (half == 0) ? sw + sw - 1.f : sw;
        float fb = __shfl(a2, lane + 24);
        float ob = __shfl(a3, lane + 24);
        c2 = fmaf(fb, c2, a2 * a3);
        float h2 = ob * tanh_fast(c2);
        if (lane < H) h2s[lane] = h2;
        LDS_SYNC();
    }

    // ---- head: tanh -> fc1(16, relu) -> fc2(24) ----
    if (lane < H) t1s[lane] = tanh_fast(h2s[lane]);
    LDS_SYNC();
    if (lane < 16) {
        float acc = b1[lane];
        #pragma unroll
        for (int j = 0; j < H; ++j) acc = fmaf(t1s[j], W1[lane * H + j], acc);
        h1s[lane] = fmaxf(acc, 0.f);                 // reuse h1s as fc1 output
    }
    LDS_SYNC();
    if (lane < H) {
        float acc = b2[lane];
        #pragma unroll
        for (int j = 0; j < 16; ++j) acc = fmaf(h1s[j], W2[lane * 16 + j], acc);
        out[(size_t)row * H + lane] = acc;
    }
}

extern "C" void kernel_launch(void* const* d_in, const int* in_sizes, int n_in,
                              void* d_out, int out_size, void* d_ws, size_t ws_size,
                              hipStream_t stream)
{
    const float* x    = (const float*)d_in[0];
    const float* Wih1 = (const float*)d_in[1];
    const float* Whh1 = (const float*)d_in[2];
    const float* bih1 = (const float*)d_in[3];
    const float* bhh1 = (const float*)d_in[4];
    const float* Wih2 = (const float*)d_in[5];
    const float* Whh2 = (const float*)d_in[6];
    const float* bih2 = (const float*)d_in[7];
    const float* bhh2 = (const float*)d_in[8];
    const float* W1   = (const float*)d_in[9];
    const float* b1   = (const float*)d_in[10];
    const float* W2   = (const float*)d_in[11];
    const float* b2   = (const float*)d_in[12];
    float* out = (float*)d_out;

    const int B = in_sizes[0] / (T * P);             // 4096
    hipLaunchKernelGGL(lstm2_wave, dim3(B), dim3(64), 0, stream,
                       x, Wih1, Whh1, bih1, bhh1, Wih2, Whh2, bih2, bhh2,
                       W1, b1, W2, b2, out);
}

// Round 4
// 411.835 us; speedup vs baseline: 1.0942x; 1.0942x over previous
//
#include <hip/hip_runtime.h>

constexpr int T = 168;
constexpr int P = 16;
constexpr int H = 24;

__device__ __forceinline__ float rcp_f(float x) { return __builtin_amdgcn_rcpf(x); }
__device__ __forceinline__ float sigm_f(float x) { return rcp_f(1.f + __expf(-x)); }
// tanh(x) = 2*sigmoid(2x) - 1
__device__ __forceinline__ float tanh_fast(float x) {
    return fmaf(2.f, rcp_f(1.f + __expf(-2.f * x)), -1.f);
}

// Opaque register pin (R3 lesson: allocator satisfies this from the unified
// AGPR side rather than raising arch-VGPR count; harmless, keeps loads hoisted).
#define KEEP(v) asm volatile("" : "+v"(v))
// Intra-wave LDS write->read ordering + compiler reorder fence.
#define LDS_SYNC() asm volatile("s_waitcnt lgkmcnt(0)" ::: "memory")

// One wave per workgroup; each wave owns TWO batch rows, time-multiplexed per
// step. Lane u in [0,24): gates {i,g} of unit u; lane 24+u: gates {f,o};
// lanes 48..63 idle (clamped). All comms intra-wave (shfl + wave-sync LDS);
// zero __syncthreads. 2048 waves = exactly 2/EU resident -> single batch.
__global__ __attribute__((amdgpu_flat_work_group_size(64, 64),
                          amdgpu_waves_per_eu(2, 2)))
void lstm2_wave2(const float* __restrict__ x,
                 const float* __restrict__ Wih1, const float* __restrict__ Whh1,
                 const float* __restrict__ bih1, const float* __restrict__ bhh1,
                 const float* __restrict__ Wih2, const float* __restrict__ Whh2,
                 const float* __restrict__ bih2, const float* __restrict__ bhh2,
                 const float* __restrict__ W1, const float* __restrict__ b1,
                 const float* __restrict__ W2, const float* __restrict__ b2,
                 float* __restrict__ out)
{
    const int lane = threadIdx.x;                 // 0..63
    const int s    = (lane < 48) ? lane : 47;     // clamp idle lanes
    const int u    = s % H;                       // unit 0..23
    const int half = s / H;                       // 0: {i,g}, 1: {f,o}
    const int q0   = half * H + u;                // i or f gate row
    const int q1   = (2 + half) * H + u;          // g or o gate row
    const int rowA = blockIdx.x * 2;
    const int rowB = rowA + 1;

    // ---- shared weights (same for both rows): 176 floats ----
    float wx0[P], wx1[P];         // Wih1 rows q0, q1
    float wh0[H], wh1[H];         // Whh1 rows q0, q1
    float vx0[H], vx1[H];         // Wih2 rows q0, q1
    float vh0[H], vh1[H];         // Whh2 rows q0, q1
    #pragma unroll
    for (int k = 0; k < P / 4; ++k) {
        float4 a = ((const float4*)(Wih1 + q0 * P))[k];
        float4 b = ((const float4*)(Wih1 + q1 * P))[k];
        wx0[4*k] = a.x; wx0[4*k+1] = a.y; wx0[4*k+2] = a.z; wx0[4*k+3] = a.w;
        wx1[4*k] = b.x; wx1[4*k+1] = b.y; wx1[4*k+2] = b.z; wx1[4*k+3] = b.w;
    }
    #pragma unroll
    for (int k = 0; k < H / 4; ++k) {
        float4 a = ((const float4*)(Whh1 + q0 * H))[k];
        float4 b = ((const float4*)(Whh1 + q1 * H))[k];
        wh0[4*k] = a.x; wh0[4*k+1] = a.y; wh0[4*k+2] = a.z; wh0[4*k+3] = a.w;
        wh1[4*k] = b.x; wh1[4*k+1] = b.y; wh1[4*k+2] = b.z; wh1[4*k+3] = b.w;
    }
    #pragma unroll
    for (int k = 0; k < H / 4; ++k) {
        float4 a = ((const float4*)(Wih2 + q0 * H))[k];
        float4 b = ((const float4*)(Wih2 + q1 * H))[k];
        vx0[4*k] = a.x; vx0[4*k+1] = a.y; vx0[4*k+2] = a.z; vx0[4*k+3] = a.w;
        vx1[4*k] = b.x; vx1[4*k+1] = b.y; vx1[4*k+2] = b.z; vx1[4*k+3] = b.w;
    }
    #pragma unroll
    for (int k = 0; k < H / 4; ++k) {
        float4 a = ((const float4*)(Whh2 + q0 * H))[k];
        float4 b = ((const float4*)(Whh2 + q1 * H))[k];
        vh0[4*k] = a.x; vh0[4*k+1] = a.y; vh0[4*k+2] = a.z; vh0[4*k+3] = a.w;
        vh1[4*k] = b.x; vh1[4*k+1] = b.y; vh1[4*k+2] = b.z; vh1[4*k+3] = b.w;
    }
    float b10 = bih1[q0] + bhh1[q0];
    float b11 = bih1[q1] + bhh1[q1];
    float b20 = bih2[q0] + bhh2[q0];
    float b21 = bih2[q1] + bhh2[q1];

    #pragma unroll
    for (int k = 0; k < P; ++k) { KEEP(wx0[k]); KEEP(wx1[k]); }
    #pragma unroll
    for (int k = 0; k < H; ++k) {
        KEEP(wh0[k]); KEEP(wh1[k]);
        KEEP(vx0[k]); KEEP(vx1[k]);
        KEEP(vh0[k]); KEEP(vh1[k]);
    }
    KEEP(b10); KEEP(b11); KEEP(b20); KEEP(b21);

    __shared__ __align__(16) float h1s[2][32];   // layer-1 h, per row
    __shared__ __align__(16) float t1s[2][32];   // tanh(h1) = layer-2 input
    __shared__ __align__(16) float h2s[2][32];   // layer-2 h

    if (lane < H) {
        h1s[0][lane] = 0.f; t1s[0][lane] = 0.f; h2s[0][lane] = 0.f;
        h1s[1][lane] = 0.f; t1s[1][lane] = 0.f; h2s[1][lane] = 0.f;
    }
    LDS_SYNC();

    const float* __restrict__ xA = x + (size_t)rowA * T * P;  // wave-uniform
    const float* __restrict__ xB = x + (size_t)rowB * T * P;  // wave-uniform

    float c1A = 0.f, c2A = 0.f, c1B = 0.f, c2B = 0.f;

    for (int t = 0; t < T; ++t) {
        // ================= layer 1, rows A and B (independent chains) ========
        float g0 = b10, g1 = b11, e0 = b10, e1 = b11;
        #pragma unroll
        for (int k = 0; k < P; ++k) {
            float xa = xA[t * P + k];                     // uniform -> s_load
            float xb = xB[t * P + k];
            g0 = fmaf(xa, wx0[k], g0);  g1 = fmaf(xa, wx1[k], g1);
            e0 = fmaf(xb, wx0[k], e0);  e1 = fmaf(xb, wx1[k], e1);
        }
        #pragma unroll
        for (int k = 0; k < H / 4; ++k) {
            float4 ha = ((const float4*)h1s[0])[k];
            float4 hb = ((const float4*)h1s[1])[k];
            g0 = fmaf(ha.x, wh0[4*k],   g0);  g1 = fmaf(ha.x, wh1[4*k],   g1);
            e0 = fmaf(hb.x, wh0[4*k],   e0);  e1 = fmaf(hb.x, wh1[4*k],   e1);
            g0 = fmaf(ha.y, wh0[4*k+1], g0);  g1 = fmaf(ha.y, wh1[4*k+1], g1);
            e0 = fmaf(hb.y, wh0[4*k+1], e0);  e1 = fmaf(hb.y, wh1[4*k+1], e1);
            g0 = fmaf(ha.z, wh0[4*k+2], g0);  g1 = fmaf(ha.z, wh1[4*k+2], g1);
            e0 = fmaf(hb.z, wh0[4*k+2], e0);  e1 = fmaf(hb.z, wh1[4*k+2], e1);
            g0 = fmaf(ha.w, wh0[4*k+3], g0);  g1 = fmaf(ha.w, wh1[4*k+3], g1);
            e0 = fmaf(hb.w, wh0[4*k+3], e0);  e1 = fmaf(hb.w, wh1[4*k+3], e1);
        }
        {
            float a0 = sigm_f(g0);
            float px = (half == 0) ? g1 + g1 : g1;
            float sv = sigm_f(px);
            float a1 = (half == 0) ? sv + sv - 1.f : sv;
            float fa = __shfl(a0, lane + 24);
            float oa = __shfl(a1, lane + 24);
            c1A = fmaf(fa, c1A, a0 * a1);
            float h1 = oa * tanh_fast(c1A);
            float th1 = tanh_fast(h1);
            if (lane < H) { h1s[0][lane] = h1; t1s[0][lane] = th1; }
        }
        {
            float a0 = sigm_f(e0);
            float px = (half == 0) ? e1 + e1 : e1;
            float sv = sigm_f(px);
            float a1 = (half == 0) ? sv + sv - 1.f : sv;
            float fa = __shfl(a0, lane + 24);
            float oa = __shfl(a1, lane + 24);
            c1B = fmaf(fa, c1B, a0 * a1);
            float h1 = oa * tanh_fast(c1B);
            float th1 = tanh_fast(h1);
            if (lane < H) { h1s[1][lane] = h1; t1s[1][lane] = th1; }
        }
        LDS_SYNC();

        // ================= layer 2, rows A and B =================
        float g2 = b20, g3 = b21, e2 = b20, e3 = b21;
        #pragma unroll
        for (int k = 0; k < H / 4; ++k) {
            float4 ta = ((const float4*)t1s[0])[k];
            float4 tb = ((const float4*)t1s[1])[k];
            g2 = fmaf(ta.x, vx0[4*k],   g2);  g3 = fmaf(ta.x, vx1[4*k],   g3);
            e2 = fmaf(tb.x, vx0[4*k],   e2);  e3 = fmaf(tb.x, vx1[4*k],   e3);
            g2 = fmaf(ta.y, vx0[4*k+1], g2);  g3 = fmaf(ta.y, vx1[4*k+1], g3);
            e2 = fmaf(tb.y, vx0[4*k+1], e2);  e3 = fmaf(tb.y, vx1[4*k+1], e3);
            g2 = fmaf(ta.z, vx0[4*k+2], g2);  g3 = fmaf(ta.z, vx1[4*k+2], g3);
            e2 = fmaf(tb.z, vx0[4*k+2], e2);  e3 = fmaf(tb.z, vx1[4*k+2], e3);
            g2 = fmaf(ta.w, vx0[4*k+3], g2);  g3 = fmaf(ta.w, vx1[4*k+3], g3);
            e2 = fmaf(tb.w, vx0[4*k+3], e2);  e3 = fmaf(tb.w, vx1[4*k+3], e3);
        }
        #pragma unroll
        for (int k = 0; k < H / 4; ++k) {
            float4 ha = ((const float4*)h2s[0])[k];
            float4 hb = ((const float4*)h2s[1])[k];
            g2 = fmaf(ha.x, vh0[4*k],   g2);  g3 = fmaf(ha.x, vh1[4*k],   g3);
            e2 = fmaf(hb.x, vh0[4*k],   e2);  e3 = fmaf(hb.x, vh1[4*k],   e3);
            g2 = fmaf(ha.y, vh0[4*k+1], g2);  g3 = fmaf(ha.y, vh1[4*k+1], g3);
            e2 = fmaf(hb.y, vh0[4*k+1], e2);  e3 = fmaf(hb.y, vh1[4*k+1], e3);
            g2 = fmaf(ha.z, vh0[4*k+2], g2);  g3 = fmaf(ha.z, vh1[4*k+2], g3);
            e2 = fmaf(hb.z, vh0[4*k+2], e2);  e3 = fmaf(hb.z, vh1[4*k+2], e3);
            g2 = fmaf(ha.w, vh0[4*k+3], g2);  g3 = fmaf(ha.w, vh1[4*k+3], g3);
            e2 = fmaf(hb.w, vh0[4*k+3], e2);  e3 = fmaf(hb.w, vh1[4*k+3], e3);
        }
        {
            float a2 = sigm_f(g2);
            float py = (half == 0) ? g3 + g3 : g3;
            float sw = sigm_f(py);
            float a3 = (half == 0) ? sw + sw - 1.f : sw;
            float fb = __shfl(a2, lane + 24);
            float ob = __shfl(a3, lane + 24);
            c2A = fmaf(fb, c2A, a2 * a3);
            if (lane < H) h2s[0][lane] = ob * tanh_fast(c2A);
        }
        {
            float a2 = sigm_f(e2);
            float py = (half == 0) ? e3 + e3 : e3;
            float sw = sigm_f(py);
            float a3 = (half == 0) ? sw + sw - 1.f : sw;
            float fb = __shfl(a2, lane + 24);
            float ob = __shfl(a3, lane + 24);
            c2B = fmaf(fb, c2B, a2 * a3);
            if (lane < H) h2s[1][lane] = ob * tanh_fast(c2B);
        }
        LDS_SYNC();
    }

    // ---- head: tanh -> fc1(16, relu) -> fc2(24), both rows ----
    if (lane < H) {
        t1s[0][lane] = tanh_fast(h2s[0][lane]);
        t1s[1][lane] = tanh_fast(h2s[1][lane]);
    }
    LDS_SYNC();
    if (lane < 16) {
        float accA = b1[lane], accB = b1[lane];
        #pragma unroll
        for (int j = 0; j < H; ++j) {
            float w = W1[lane * H + j];
            accA = fmaf(t1s[0][j], w, accA);
            accB = fmaf(t1s[1][j], w, accB);
        }
        h1s[0][lane] = fmaxf(accA, 0.f);
        h1s[1][lane] = fmaxf(accB, 0.f);
    }
    LDS_SYNC();
    if (lane < H) {
        float accA = b2[lane], accB = b2[lane];
        #pragma unroll
        for (int j = 0; j < 16; ++j) {
            float w = W2[lane * 16 + j];
            accA = fmaf(h1s[0][j], w, accA);
            accB = fmaf(h1s[1][j], w, accB);
        }
        out[(size_t)rowA * H + lane] = accA;
        out[(size_t)rowB * H + lane] = accB;
    }
}

extern "C" void kernel_launch(void* const* d_in, const int* in_sizes, int n_in,
                              void* d_out, int out_size, void* d_ws, size_t ws_size,
                              hipStream_t stream)
{
    const float* x    = (const float*)d_in[0];
    const float* Wih1 = (const float*)d_in[1];
    const float* Whh1 = (const float*)d_in[2];
    const float* bih1 = (const float*)d_in[3];
    const float* bhh1 = (const float*)d_in[4];
    const float* Wih2 = (const float*)d_in[5];
    const float* Whh2 = (const float*)d_in[6];
    const float* bih2 = (const float*)d_in[7];
    const float* bhh2 = (const float*)d_in[8];
    const float* W1   = (const float*)d_in[9];
    const float* b1   = (const float*)d_in[10];
    const float* W2   = (const float*)d_in[11];
    const float* b2   = (const float*)d_in[12];
    float* out = (float*)d_out;

    const int B = in_sizes[0] / (T * P);             // 4096
    hipLaunchKernelGGL(lstm2_wave2, dim3(B / 2), dim3(64), 0, stream,
                       x, Wih1, Whh1, bih1, bhh1, Wih2, Whh2, bih2, bhh2,
                       W1, b1, W2, b2, out);
}